// Round 1
// baseline (9509.740 us; speedup 1.0000x reference)
//
#include <hip/hip_runtime.h>
#include <math.h>

#define BB 2
#define SS 2048
#define DIM 1024
#define NH 16
#define DH 64

// Tiled fp32 GEMM: C = A(MxK) @ W(KxN) + bias
// mode 0: C row-major [M,N]
// mode 1: split-heads: m=b*S+s, n=h*DH+d -> C[((b*H+h)*S+s)*DH+d]
__global__ void gemm_bias(const float* __restrict__ A, const float* __restrict__ W,
                          const float* __restrict__ bias, float* __restrict__ C,
                          int M, int N, int K, int mode) {
    __shared__ float As[16][17];
    __shared__ float Ws[16][17];
    int tx = threadIdx.x, ty = threadIdx.y;
    int m = blockIdx.y * 16 + ty;
    int n = blockIdx.x * 16 + tx;
    float acc = 0.f;
    for (int k0 = 0; k0 < K; k0 += 16) {
        As[ty][tx] = A[m * K + k0 + tx];
        Ws[ty][tx] = W[(k0 + ty) * N + n];
        __syncthreads();
#pragma unroll
        for (int kk = 0; kk < 16; ++kk) acc += As[ty][kk] * Ws[kk][tx];
        __syncthreads();
    }
    acc += bias[n];
    if (mode == 0) {
        C[m * N + n] = acc;
    } else {
        int b = m / SS, s = m % SS, h = n / DH, d = n % DH;
        C[((b * NH + h) * SS + s) * DH + d] = acc;
    }
}

// One block (256 threads) per (b*H+h, q). Q/K/V in [B,H,S,DH] layout.
// ctx written in combined [B,S,H*DH] layout.
__global__ void attn_kernel(const float* __restrict__ Q, const float* __restrict__ Km,
                            const float* __restrict__ V, const float* __restrict__ mask,
                            float* __restrict__ ctx) {
    int q  = blockIdx.x;
    int bh = blockIdx.y;
    int b  = bh / NH;
    int h  = bh % NH;
    const float* Qrow  = Q  + (size_t)(bh * SS + q) * DH;
    const float* Kbase = Km + (size_t)bh * SS * DH;
    const float* Vbase = V  + (size_t)bh * SS * DH;

    __shared__ float qv[DH];
    __shared__ float sc[SS];     // 8 KB scores
    __shared__ float red[256];

    int tid = threadIdx.x;
    if (tid < DH) qv[tid] = Qrow[tid];
    __syncthreads();

    const float scale = 0.125f;  // 1/sqrt(64)
    for (int k = tid; k < SS; k += 256) {
        const float* Krow = Kbase + (size_t)k * DH;
        float d = 0.f;
#pragma unroll
        for (int i = 0; i < DH; ++i) d += qv[i] * Krow[i];
        sc[k] = d * scale - 1000000.0f * (1.0f - mask[b * SS + k]);
    }
    __syncthreads();

    // max reduction
    float m = -1e30f;
    for (int k = tid; k < SS; k += 256) m = fmaxf(m, sc[k]);
    red[tid] = m;
    __syncthreads();
    for (int off = 128; off > 0; off >>= 1) {
        if (tid < off) red[tid] = fmaxf(red[tid], red[tid + off]);
        __syncthreads();
    }
    m = red[0];
    __syncthreads();

    // exp + sum
    float ssum = 0.f;
    for (int k = tid; k < SS; k += 256) {
        float e = __expf(sc[k] - m);
        sc[k] = e;
        ssum += e;
    }
    red[tid] = ssum;
    __syncthreads();
    for (int off = 128; off > 0; off >>= 1) {
        if (tid < off) red[tid] += red[tid + off];
        __syncthreads();
    }
    float inv = 1.0f / red[0];
    __syncthreads();

    // ctx: 4 groups of 64 lanes; lane d handles dim d, group g handles k%4==g
    int d = tid & 63;
    int g = tid >> 6;
    float acc = 0.f;
    for (int k = g; k < SS; k += 4) {
        acc += sc[k] * Vbase[(size_t)k * DH + d];
    }
    red[tid] = acc;
    __syncthreads();
    if (g == 0) {
        float r = red[d] + red[64 + d] + red[128 + d] + red[192 + d];
        ctx[((size_t)b * SS + q) * (NH * DH) + h * DH + d] = r * inv;
    }
}

extern "C" void kernel_launch(void* const* d_in, const int* in_sizes, int n_in,
                              void* d_out, int out_size, void* d_ws, size_t ws_size,
                              hipStream_t stream) {
    const float* X    = (const float*)d_in[0];
    const float* mask = (const float*)d_in[1];
    const float* Wq   = (const float*)d_in[2];
    const float* bq   = (const float*)d_in[3];
    const float* Wk   = (const float*)d_in[4];
    const float* bk   = (const float*)d_in[5];
    const float* Wv   = (const float*)d_in[6];
    const float* bv   = (const float*)d_in[7];
    const float* Wo   = (const float*)d_in[8];
    const float* bo   = (const float*)d_in[9];
    float* out = (float*)d_out;

    const size_t BSD = (size_t)BB * SS * NH * DH;  // 4,194,304
    float* ws = (float*)d_ws;
    float* Qw  = ws;
    float* Kw  = ws + BSD;
    float* Vw  = ws + 2 * BSD;
    float* Cw  = ws + 3 * BSD;

    const int M = BB * SS;       // 4096
    const int N = NH * DH;       // 1024
    const int K = DIM;           // 1024

    dim3 blk(16, 16);
    dim3 grd(N / 16, M / 16);
    gemm_bias<<<grd, blk, 0, stream>>>(X, Wq, bq, Qw, M, N, K, 1);
    gemm_bias<<<grd, blk, 0, stream>>>(X, Wk, bk, Kw, M, N, K, 1);
    gemm_bias<<<grd, blk, 0, stream>>>(X, Wv, bv, Vw, M, N, K, 1);

    dim3 agrd(SS, BB * NH);
    attn_kernel<<<agrd, 256, 0, stream>>>(Qw, Kw, Vw, mask, Cw);

    gemm_bias<<<grd, blk, 0, stream>>>(Cw, Wo, bo, out, M, N, K, 0);
}

// Round 2
// 2389.643 us; speedup vs baseline: 3.9796x; 3.9796x over previous
//
#include <hip/hip_runtime.h>
#include <hip/hip_bf16.h>
#include <math.h>

#define BB 2
#define SS 2048
#define DIM 1024
#define NH 16
#define DH 64

typedef __bf16 bf16x8 __attribute__((ext_vector_type(8)));
typedef float f32x4 __attribute__((ext_vector_type(4)));

// ---------------- fp32 tiled GEMM (final projection): C = A@W + bias ----------------
__global__ void gemm_bias_f32(const float* __restrict__ A, const float* __restrict__ W,
                              const float* __restrict__ bias, float* __restrict__ C,
                              int M, int N, int K) {
    __shared__ float As[16][17];
    __shared__ float Ws[16][17];
    int tx = threadIdx.x, ty = threadIdx.y;
    int m = blockIdx.y * 16 + ty;
    int n = blockIdx.x * 16 + tx;
    float acc = 0.f;
    for (int k0 = 0; k0 < K; k0 += 16) {
        As[ty][tx] = A[m * K + k0 + tx];
        Ws[ty][tx] = W[(k0 + ty) * N + n];
        __syncthreads();
#pragma unroll
        for (int kk = 0; kk < 16; ++kk) acc += As[ty][kk] * Ws[kk][tx];
        __syncthreads();
    }
    C[m * N + n] = acc + bias[n];
}

// ------------- fp32 GEMM, bf16 output in attention layouts -------------
// mode 1: split-heads  [B,H,S,DH]   (Q, K)
// mode 2: transposed   [B,H,DH,S]   (V^T)
__global__ void gemm_bias_bf16(const float* __restrict__ A, const float* __restrict__ W,
                               const float* __restrict__ bias, __hip_bfloat16* __restrict__ C,
                               int M, int N, int K, int mode) {
    __shared__ float As[16][17];
    __shared__ float Ws[16][17];
    int tx = threadIdx.x, ty = threadIdx.y;
    int m = blockIdx.y * 16 + ty;
    int n = blockIdx.x * 16 + tx;
    float acc = 0.f;
    for (int k0 = 0; k0 < K; k0 += 16) {
        As[ty][tx] = A[m * K + k0 + tx];
        Ws[ty][tx] = W[(k0 + ty) * N + n];
        __syncthreads();
#pragma unroll
        for (int kk = 0; kk < 16; ++kk) acc += As[ty][kk] * Ws[kk][tx];
        __syncthreads();
    }
    acc += bias[n];
    int b = m >> 11, s = m & (SS - 1);
    int h = n >> 6,  d = n & (DH - 1);
    size_t idx;
    if (mode == 1) idx = (((size_t)(b * NH + h)) * SS + s) * DH + d;
    else           idx = (((size_t)(b * NH + h)) * DH + d) * SS + s;
    C[idx] = __float2bfloat16(acc);
}

// ---------------- flash attention, bf16 MFMA ----------------
// Q,K: [B,H,S,DH] bf16.  Vt: [B,H,DH,S] bf16.  ctx out: [B,S,H*DH] fp32.
// Block: 256 threads (4 waves), 64-query tile. Wave w owns query rows [16w,16w+16).
__global__ void flash_attn(const __hip_bfloat16* __restrict__ Q,
                           const __hip_bfloat16* __restrict__ K,
                           const __hip_bfloat16* __restrict__ Vt,
                           const float* __restrict__ mask,
                           float* __restrict__ ctx) {
    int bh = blockIdx.y;
    int b = bh >> 4, h = bh & (NH - 1);
    int q0 = blockIdx.x * 64;
    int tid = threadIdx.x;
    int wave = tid >> 6, lane = tid & 63, quad = lane >> 4, l16 = lane & 15;

    __shared__ __hip_bfloat16 Pl[4][16][72];   // per-wave P staging (C-layout -> A-layout)

    // Q fragments for this wave's 16 rows (A-operand layout: m=l16, k=quad*8+j)
    const __hip_bfloat16* Qrow = Q + ((size_t)bh * SS + q0 + wave * 16 + l16) * DH;
    bf16x8 aq0 = *(const bf16x8*)(Qrow + quad * 8);
    bf16x8 aq1 = *(const bf16x8*)(Qrow + 32 + quad * 8);

    const __hip_bfloat16* Kbase = K + (size_t)bh * SS * DH;
    const __hip_bfloat16* Vbase = Vt + (size_t)bh * DH * SS;
    const float* mbase = mask + b * SS;

    f32x4 O[4];
#pragma unroll
    for (int i = 0; i < 4; ++i) { O[i][0] = 0.f; O[i][1] = 0.f; O[i][2] = 0.f; O[i][3] = 0.f; }
    float mrow[4] = {-1e30f, -1e30f, -1e30f, -1e30f};
    float lrow[4] = {0.f, 0.f, 0.f, 0.f};

    for (int k0 = 0; k0 < SS; k0 += 64) {
        // ---- S = Q K^T * scale - mask penalty  (C-layout: row=quad*4+r, col=l16 per 16-col block)
        f32x4 S[4];
#pragma unroll
        for (int nb = 0; nb < 4; ++nb) {
            const __hip_bfloat16* Kr = Kbase + (size_t)(k0 + nb * 16 + l16) * DH + quad * 8;
            bf16x8 bk0 = *(const bf16x8*)(Kr);
            bf16x8 bk1 = *(const bf16x8*)(Kr + 32);
            f32x4 s;
            s[0] = 0.f; s[1] = 0.f; s[2] = 0.f; s[3] = 0.f;
            s = __builtin_amdgcn_mfma_f32_16x16x32_bf16(aq0, bk0, s, 0, 0, 0);
            s = __builtin_amdgcn_mfma_f32_16x16x32_bf16(aq1, bk1, s, 0, 0, 0);
            float pen = 1000000.0f * (1.0f - mbase[k0 + nb * 16 + l16]);
#pragma unroll
            for (int r = 0; r < 4; ++r) s[r] = s[r] * 0.125f - pen;
            S[nb] = s;
        }
        // ---- row max (across 4 col-blocks in-lane, then 16 lanes cross-lane)
        float rm[4];
#pragma unroll
        for (int r = 0; r < 4; ++r)
            rm[r] = fmaxf(fmaxf(S[0][r], S[1][r]), fmaxf(S[2][r], S[3][r]));
#pragma unroll
        for (int off = 1; off < 16; off <<= 1)
#pragma unroll
            for (int r = 0; r < 4; ++r)
                rm[r] = fmaxf(rm[r], __shfl_xor(rm[r], off, 64));
        float alpha[4];
#pragma unroll
        for (int r = 0; r < 4; ++r) {
            float mn = fmaxf(mrow[r], rm[r]);
            alpha[r] = __expf(mrow[r] - mn);
            mrow[r] = mn;
        }
        // ---- P = exp(S - m), row sums
        float rs[4] = {0.f, 0.f, 0.f, 0.f};
#pragma unroll
        for (int nb = 0; nb < 4; ++nb)
#pragma unroll
            for (int r = 0; r < 4; ++r) {
                float p = __expf(S[nb][r] - mrow[r]);
                S[nb][r] = p;
                rs[r] += p;
            }
#pragma unroll
        for (int off = 1; off < 16; off <<= 1)
#pragma unroll
            for (int r = 0; r < 4; ++r)
                rs[r] += __shfl_xor(rs[r], off, 64);
#pragma unroll
        for (int r = 0; r < 4; ++r)
            lrow[r] = lrow[r] * alpha[r] + rs[r];
        // ---- P (C-layout) -> LDS -> A-layout
#pragma unroll
        for (int nb = 0; nb < 4; ++nb)
#pragma unroll
            for (int r = 0; r < 4; ++r)
                Pl[wave][quad * 4 + r][nb * 16 + l16] = __float2bfloat16(S[nb][r]);
        // ---- rescale O
#pragma unroll
        for (int nb2 = 0; nb2 < 4; ++nb2)
#pragma unroll
            for (int r = 0; r < 4; ++r)
                O[nb2][r] *= alpha[r];
        // ---- O += P @ V   (A = P from LDS, B = V^T rows from global)
        bf16x8 ap0 = *(const bf16x8*)(&Pl[wave][l16][quad * 8]);
        bf16x8 ap1 = *(const bf16x8*)(&Pl[wave][l16][32 + quad * 8]);
#pragma unroll
        for (int nb2 = 0; nb2 < 4; ++nb2) {
            const __hip_bfloat16* Vr = Vbase + (size_t)(nb2 * 16 + l16) * SS + k0 + quad * 8;
            bf16x8 bv0 = *(const bf16x8*)(Vr);
            bf16x8 bv1 = *(const bf16x8*)(Vr + 32);
            O[nb2] = __builtin_amdgcn_mfma_f32_16x16x32_bf16(ap0, bv0, O[nb2], 0, 0, 0);
            O[nb2] = __builtin_amdgcn_mfma_f32_16x16x32_bf16(ap1, bv1, O[nb2], 0, 0, 0);
        }
    }
    // ---- epilogue: ctx[b][q][h*64+d] = O / l
#pragma unroll
    for (int nb2 = 0; nb2 < 4; ++nb2)
#pragma unroll
        for (int r = 0; r < 4; ++r) {
            size_t row = (size_t)b * SS + q0 + wave * 16 + quad * 4 + r;
            ctx[row * (NH * DH) + h * DH + nb2 * 16 + l16] = O[nb2][r] / lrow[r];
        }
}

extern "C" void kernel_launch(void* const* d_in, const int* in_sizes, int n_in,
                              void* d_out, int out_size, void* d_ws, size_t ws_size,
                              hipStream_t stream) {
    const float* X    = (const float*)d_in[0];
    const float* mask = (const float*)d_in[1];
    const float* Wq   = (const float*)d_in[2];
    const float* bq   = (const float*)d_in[3];
    const float* Wk   = (const float*)d_in[4];
    const float* bk   = (const float*)d_in[5];
    const float* Wv   = (const float*)d_in[6];
    const float* bv   = (const float*)d_in[7];
    const float* Wo   = (const float*)d_in[8];
    const float* bo   = (const float*)d_in[9];
    float* out = (float*)d_out;

    const size_t BSD = (size_t)BB * SS * NH * DH;     // 4,194,304 elements
    char* ws = (char*)d_ws;
    __hip_bfloat16* Qw = (__hip_bfloat16*)ws;                       // 8 MB
    __hip_bfloat16* Kw = (__hip_bfloat16*)(ws + BSD * 2);           // 8 MB
    __hip_bfloat16* Vt = (__hip_bfloat16*)(ws + BSD * 4);           // 8 MB
    float*          Cw = (float*)(ws + BSD * 6);                    // 16 MB

    const int M = BB * SS;   // 4096
    const int N = NH * DH;   // 1024
    const int K = DIM;       // 1024

    dim3 blk(16, 16);
    dim3 grd(N / 16, M / 16);
    gemm_bias_bf16<<<grd, blk, 0, stream>>>(X, Wq, bq, Qw, M, N, K, 1);
    gemm_bias_bf16<<<grd, blk, 0, stream>>>(X, Wk, bk, Kw, M, N, K, 1);
    gemm_bias_bf16<<<grd, blk, 0, stream>>>(X, Wv, bv, Vt, M, N, K, 2);

    dim3 agrd(SS / 64, BB * NH);
    flash_attn<<<agrd, 256, 0, stream>>>(Qw, Kw, Vt, mask, Cw);

    gemm_bias_f32<<<grd, blk, 0, stream>>>(Cw, Wo, bo, out, M, N, K);
}

// Round 3
// 481.071 us; speedup vs baseline: 19.7679x; 4.9673x over previous
//
#include <hip/hip_runtime.h>
#include <hip/hip_bf16.h>
#include <math.h>

#define BB 2
#define SS 2048
#define DIM 1024
#define NH 16
#define DH 64

typedef __bf16 bf16x8 __attribute__((ext_vector_type(8)));
typedef float f32x4 __attribute__((ext_vector_type(4)));

__device__ __forceinline__ void glds16(const __hip_bfloat16* g, __hip_bfloat16* l) {
    __builtin_amdgcn_global_load_lds(
        (const __attribute__((address_space(1))) void*)g,
        (__attribute__((address_space(3))) void*)l, 16, 0, 0);
}

// ---------------- prep: split fp32 -> bf16 hi + lo ----------------
__global__ void split_f32(const float4* __restrict__ in,
                          ushort4* __restrict__ hi, ushort4* __restrict__ lo) {
    int i = blockIdx.x * 256 + threadIdx.x;
    float4 v = in[i];
    ushort4 h, l;
    __hip_bfloat16 t;
    t = __float2bfloat16(v.x); h.x = *(ushort*)&t; t = __float2bfloat16(v.x - __bfloat162float(t)); l.x = *(ushort*)&t;
    t = __float2bfloat16(v.y); h.y = *(ushort*)&t; t = __float2bfloat16(v.y - __bfloat162float(t)); l.y = *(ushort*)&t;
    t = __float2bfloat16(v.z); h.z = *(ushort*)&t; t = __float2bfloat16(v.z - __bfloat162float(t)); l.z = *(ushort*)&t;
    t = __float2bfloat16(v.w); h.w = *(ushort*)&t; t = __float2bfloat16(v.w - __bfloat162float(t)); l.w = *(ushort*)&t;
    hi[i] = h; lo[i] = l;
}

// ---------------- prep: transpose W [K,N] -> T [N,K], split hi/lo ----------------
__global__ void trans_split(const float* __restrict__ W,
                            __hip_bfloat16* __restrict__ Thi, __hip_bfloat16* __restrict__ Tlo) {
    __shared__ float tile[32][33];
    int k0 = blockIdx.x * 32, n0 = blockIdx.y * 32;
    int t = threadIdx.x;
    int r = t >> 3, c = (t & 7) << 2;
    float4 v = *(const float4*)&W[(size_t)(k0 + r) * DIM + n0 + c];
    tile[r][c] = v.x; tile[r][c + 1] = v.y; tile[r][c + 2] = v.z; tile[r][c + 3] = v.w;
    __syncthreads();
    size_t base = (size_t)(n0 + r) * DIM + k0 + c;
#pragma unroll
    for (int i = 0; i < 4; ++i) {
        float x = tile[c + i][r];
        __hip_bfloat16 h = __float2bfloat16(x);
        Thi[base + i] = h;
        Tlo[base + i] = __float2bfloat16(x - __bfloat162float(h));
    }
}

// ---------------- split-bf16 3-term MFMA GEMM ----------------
// C[m][n] = sum_k (Ahi+Alo)[m][k]*(Bhi+Blo)[n][k] + bias  (AloBlo dropped)
// A: [M,1024] bf16 hi/lo.  B: [N,1024] bf16 hi/lo (row-major in k).
// mode 0: of32[m*1024+n] = v + bias[n]                      (final out)
// mode 1: obf[((b*16+h)*2048+s)*64+d], m=b*2048+s, n=h*64+d (Q,K split-heads)
// mode 3: obf[((b*16+h)*64+d)*2048+s], m=h*64+d,  n=b*2048+s (V^T, swapped operands)
#define BM 128
#define BN 64
#define BK 32
__global__ __launch_bounds__(256) void gemm3term(
    const __hip_bfloat16* __restrict__ Ahi, const __hip_bfloat16* __restrict__ Alo,
    const __hip_bfloat16* __restrict__ Bhi, const __hip_bfloat16* __restrict__ Blo,
    const float* __restrict__ bias,
    __hip_bfloat16* __restrict__ obf, float* __restrict__ of32, int mode) {
    __shared__ alignas(16) __hip_bfloat16 sAh[BM * BK];
    __shared__ alignas(16) __hip_bfloat16 sAl[BM * BK];
    __shared__ alignas(16) __hip_bfloat16 sBh[BN * BK];
    __shared__ alignas(16) __hip_bfloat16 sBl[BN * BK];
    const int K = 1024;
    int tid = threadIdx.x;
    int wave = tid >> 6, lane = tid & 63, quad = lane >> 4, l16 = lane & 15;
    int m0 = blockIdx.y * BM, n0 = blockIdx.x * BN;
    int mo = (wave >> 1) * 64, no = (wave & 1) * 32;

    f32x4 acc[4][2];
#pragma unroll
    for (int i = 0; i < 4; ++i)
#pragma unroll
        for (int j = 0; j < 2; ++j) acc[i][j] = (f32x4){0.f, 0.f, 0.f, 0.f};

    int ar = tid >> 2;            // 0..63
    int ac = (tid & 3) << 3;      // 0,8,16,24
    const __hip_bfloat16* gAh = Ahi + (size_t)(m0 + ar) * K + ac;
    const __hip_bfloat16* gAl = Alo + (size_t)(m0 + ar) * K + ac;
    const __hip_bfloat16* gBh = Bhi + (size_t)(n0 + ar) * K + ac;
    const __hip_bfloat16* gBl = Blo + (size_t)(n0 + ar) * K + ac;
    __hip_bfloat16* lAh0 = &sAh[ar * BK + ac];
    __hip_bfloat16* lAh1 = &sAh[(ar + 64) * BK + ac];
    __hip_bfloat16* lAl0 = &sAl[ar * BK + ac];
    __hip_bfloat16* lAl1 = &sAl[(ar + 64) * BK + ac];
    __hip_bfloat16* lBh  = &sBh[ar * BK + ac];
    __hip_bfloat16* lBl  = &sBl[ar * BK + ac];

    for (int k0 = 0; k0 < K; k0 += BK) {
        __syncthreads();
        glds16(gAh + k0, lAh0);
        glds16(gAh + (size_t)64 * K + k0, lAh1);
        glds16(gAl + k0, lAl0);
        glds16(gAl + (size_t)64 * K + k0, lAl1);
        glds16(gBh + k0, lBh);
        glds16(gBl + k0, lBl);
        __syncthreads();

        bf16x8 a_h[4], a_l[4], b_h[2], b_l[2];
#pragma unroll
        for (int i = 0; i < 4; ++i) {
            int off = (mo + i * 16 + l16) * BK + quad * 8;
            a_h[i] = *(const bf16x8*)&sAh[off];
            a_l[i] = *(const bf16x8*)&sAl[off];
        }
#pragma unroll
        for (int j = 0; j < 2; ++j) {
            int off = (no + j * 16 + l16) * BK + quad * 8;
            b_h[j] = *(const bf16x8*)&sBh[off];
            b_l[j] = *(const bf16x8*)&sBl[off];
        }
#pragma unroll
        for (int i = 0; i < 4; ++i)
#pragma unroll
            for (int j = 0; j < 2; ++j) {
                acc[i][j] = __builtin_amdgcn_mfma_f32_16x16x32_bf16(a_h[i], b_h[j], acc[i][j], 0, 0, 0);
                acc[i][j] = __builtin_amdgcn_mfma_f32_16x16x32_bf16(a_h[i], b_l[j], acc[i][j], 0, 0, 0);
                acc[i][j] = __builtin_amdgcn_mfma_f32_16x16x32_bf16(a_l[i], b_h[j], acc[i][j], 0, 0, 0);
            }
    }

#pragma unroll
    for (int i = 0; i < 4; ++i)
#pragma unroll
        for (int j = 0; j < 2; ++j) {
            int gmb = m0 + mo + i * 16 + quad * 4;
            int gn  = n0 + no + j * 16 + l16;
#pragma unroll
            for (int r = 0; r < 4; ++r) {
                int gm = gmb + r;
                float v = acc[i][j][r];
                if (mode == 0) {
                    of32[(size_t)gm * 1024 + gn] = v + bias[gn];
                } else if (mode == 1) {
                    v += bias[gn];
                    int b = gm >> 11, s = gm & 2047, h = gn >> 6, d = gn & 63;
                    obf[(((size_t)(b * NH + h)) * SS + s) * DH + d] = __float2bfloat16(v);
                } else {  // mode 3: operands swapped, C = (X@W)^T
                    v += bias[gm];
                    int h = gm >> 6, d = gm & 63, b = gn >> 11, s = gn & 2047;
                    obf[(((size_t)(b * NH + h)) * DH + d) * SS + s] = __float2bfloat16(v);
                }
            }
        }
}

// ---------------- flash attention, bf16 MFMA ----------------
// Q,K: [B,H,S,DH] bf16.  Vt: [B,H,DH,S] bf16.  ctx out: hi/lo bf16 [B,S,H*DH].
__global__ void flash_attn(const __hip_bfloat16* __restrict__ Q,
                           const __hip_bfloat16* __restrict__ K,
                           const __hip_bfloat16* __restrict__ Vt,
                           const float* __restrict__ mask,
                           __hip_bfloat16* __restrict__ chi,
                           __hip_bfloat16* __restrict__ clo) {
    int bh = blockIdx.y;
    int b = bh >> 4, h = bh & (NH - 1);
    int q0 = blockIdx.x * 64;
    int tid = threadIdx.x;
    int wave = tid >> 6, lane = tid & 63, quad = lane >> 4, l16 = lane & 15;

    __shared__ __hip_bfloat16 Pl[4][16][72];

    const __hip_bfloat16* Qrow = Q + ((size_t)bh * SS + q0 + wave * 16 + l16) * DH;
    bf16x8 aq0 = *(const bf16x8*)(Qrow + quad * 8);
    bf16x8 aq1 = *(const bf16x8*)(Qrow + 32 + quad * 8);

    const __hip_bfloat16* Kbase = K + (size_t)bh * SS * DH;
    const __hip_bfloat16* Vbase = Vt + (size_t)bh * DH * SS;
    const float* mbase = mask + b * SS;

    f32x4 O[4];
#pragma unroll
    for (int i = 0; i < 4; ++i) O[i] = (f32x4){0.f, 0.f, 0.f, 0.f};
    float mrow[4] = {-1e30f, -1e30f, -1e30f, -1e30f};
    float lrow[4] = {0.f, 0.f, 0.f, 0.f};

    for (int k0 = 0; k0 < SS; k0 += 64) {
        f32x4 S[4];
#pragma unroll
        for (int nb = 0; nb < 4; ++nb) {
            const __hip_bfloat16* Kr = Kbase + (size_t)(k0 + nb * 16 + l16) * DH + quad * 8;
            bf16x8 bk0 = *(const bf16x8*)(Kr);
            bf16x8 bk1 = *(const bf16x8*)(Kr + 32);
            f32x4 s = (f32x4){0.f, 0.f, 0.f, 0.f};
            s = __builtin_amdgcn_mfma_f32_16x16x32_bf16(aq0, bk0, s, 0, 0, 0);
            s = __builtin_amdgcn_mfma_f32_16x16x32_bf16(aq1, bk1, s, 0, 0, 0);
            float pen = 1000000.0f * (1.0f - mbase[k0 + nb * 16 + l16]);
#pragma unroll
            for (int r = 0; r < 4; ++r) s[r] = s[r] * 0.125f - pen;
            S[nb] = s;
        }
        float rm[4];
#pragma unroll
        for (int r = 0; r < 4; ++r)
            rm[r] = fmaxf(fmaxf(S[0][r], S[1][r]), fmaxf(S[2][r], S[3][r]));
#pragma unroll
        for (int off = 1; off < 16; off <<= 1)
#pragma unroll
            for (int r = 0; r < 4; ++r)
                rm[r] = fmaxf(rm[r], __shfl_xor(rm[r], off, 64));
        float alpha[4];
#pragma unroll
        for (int r = 0; r < 4; ++r) {
            float mn = fmaxf(mrow[r], rm[r]);
            alpha[r] = __expf(mrow[r] - mn);
            mrow[r] = mn;
        }
        float rs[4] = {0.f, 0.f, 0.f, 0.f};
#pragma unroll
        for (int nb = 0; nb < 4; ++nb)
#pragma unroll
            for (int r = 0; r < 4; ++r) {
                float p = __expf(S[nb][r] - mrow[r]);
                S[nb][r] = p;
                rs[r] += p;
            }
#pragma unroll
        for (int off = 1; off < 16; off <<= 1)
#pragma unroll
            for (int r = 0; r < 4; ++r)
                rs[r] += __shfl_xor(rs[r], off, 64);
#pragma unroll
        for (int r = 0; r < 4; ++r)
            lrow[r] = lrow[r] * alpha[r] + rs[r];
#pragma unroll
        for (int nb = 0; nb < 4; ++nb)
#pragma unroll
            for (int r = 0; r < 4; ++r)
                Pl[wave][quad * 4 + r][nb * 16 + l16] = __float2bfloat16(S[nb][r]);
#pragma unroll
        for (int nb2 = 0; nb2 < 4; ++nb2)
#pragma unroll
            for (int r = 0; r < 4; ++r)
                O[nb2][r] *= alpha[r];
        bf16x8 ap0 = *(const bf16x8*)(&Pl[wave][l16][quad * 8]);
        bf16x8 ap1 = *(const bf16x8*)(&Pl[wave][l16][32 + quad * 8]);
#pragma unroll
        for (int nb2 = 0; nb2 < 4; ++nb2) {
            const __hip_bfloat16* Vr = Vbase + (size_t)(nb2 * 16 + l16) * SS + k0 + quad * 8;
            bf16x8 bv0 = *(const bf16x8*)(Vr);
            bf16x8 bv1 = *(const bf16x8*)(Vr + 32);
            O[nb2] = __builtin_amdgcn_mfma_f32_16x16x32_bf16(ap0, bv0, O[nb2], 0, 0, 0);
            O[nb2] = __builtin_amdgcn_mfma_f32_16x16x32_bf16(ap1, bv1, O[nb2], 0, 0, 0);
        }
    }
#pragma unroll
    for (int nb2 = 0; nb2 < 4; ++nb2)
#pragma unroll
        for (int r = 0; r < 4; ++r) {
            size_t row = (size_t)b * SS + q0 + wave * 16 + quad * 4 + r;
            float v = O[nb2][r] / lrow[r];
            size_t idx = row * (NH * DH) + h * DH + nb2 * 16 + l16;
            __hip_bfloat16 hi = __float2bfloat16(v);
            chi[idx] = hi;
            clo[idx] = __float2bfloat16(v - __bfloat162float(hi));
        }
}

extern "C" void kernel_launch(void* const* d_in, const int* in_sizes, int n_in,
                              void* d_out, int out_size, void* d_ws, size_t ws_size,
                              hipStream_t stream) {
    const float* X    = (const float*)d_in[0];
    const float* mask = (const float*)d_in[1];
    const float* Wq   = (const float*)d_in[2];
    const float* bq   = (const float*)d_in[3];
    const float* Wk   = (const float*)d_in[4];
    const float* bk   = (const float*)d_in[5];
    const float* Wv   = (const float*)d_in[6];
    const float* bv   = (const float*)d_in[7];
    const float* Wo   = (const float*)d_in[8];
    const float* bo   = (const float*)d_in[9];
    float* out = (float*)d_out;

    const size_t MB = 1u << 20;
    char* ws = (char*)d_ws;
    __hip_bfloat16* Xhi  = (__hip_bfloat16*)(ws);            // 8 MB (later ctx_hi)
    __hip_bfloat16* Xlo  = (__hip_bfloat16*)(ws + 8 * MB);   // 8 MB (later ctx_lo)
    __hip_bfloat16* Wthi = (__hip_bfloat16*)(ws + 16 * MB);  // 2 MB
    __hip_bfloat16* Wtlo = (__hip_bfloat16*)(ws + 18 * MB);  // 2 MB
    __hip_bfloat16* Qw   = (__hip_bfloat16*)(ws + 20 * MB);  // 8 MB
    __hip_bfloat16* Kw   = (__hip_bfloat16*)(ws + 28 * MB);  // 8 MB
    __hip_bfloat16* Vt   = (__hip_bfloat16*)(ws + 36 * MB);  // 8 MB

    // split X (4096x1024 fp32 -> bf16 hi/lo)
    split_f32<<<4096, 256, 0, stream>>>((const float4*)X, (ushort4*)Xhi, (ushort4*)Xlo);

    dim3 tgrd(32, 32);
    dim3 ggrd(DIM / BN, (BB * SS) / BM);      // (16, 32) for M=4096,N=1024
    dim3 vgrd((BB * SS) / BN, DIM / BM);      // (64, 8)  for M=1024,N=4096 (swapped)

    // Q = X@Wq + bq  (mode 1)
    trans_split<<<tgrd, 256, 0, stream>>>(Wq, Wthi, Wtlo);
    gemm3term<<<ggrd, 256, 0, stream>>>(Xhi, Xlo, Wthi, Wtlo, bq, Qw, nullptr, 1);
    // K = X@Wk + bk  (mode 1)
    trans_split<<<tgrd, 256, 0, stream>>>(Wk, Wthi, Wtlo);
    gemm3term<<<ggrd, 256, 0, stream>>>(Xhi, Xlo, Wthi, Wtlo, bk, Kw, nullptr, 1);
    // V^T = (X@Wv + bv)^T  (mode 3: A=Wt, B=X)
    trans_split<<<tgrd, 256, 0, stream>>>(Wv, Wthi, Wtlo);
    gemm3term<<<vgrd, 256, 0, stream>>>(Wthi, Wtlo, Xhi, Xlo, bv, Vt, nullptr, 3);

    // attention -> ctx hi/lo (reuses X buffers)
    dim3 agrd(SS / 64, BB * NH);
    flash_attn<<<agrd, 256, 0, stream>>>(Qw, Kw, Vt, mask, Xhi, Xlo);

    // out = ctx@Wo + bo  (mode 0, fp32)
    trans_split<<<tgrd, 256, 0, stream>>>(Wo, Wthi, Wtlo);
    gemm3term<<<ggrd, 256, 0, stream>>>(Xhi, Xlo, Wthi, Wtlo, bo, nullptr, out, 0);
}

// Round 4
// 458.433 us; speedup vs baseline: 20.7440x; 1.0494x over previous
//
#include <hip/hip_runtime.h>
#include <hip/hip_bf16.h>
#include <math.h>

#define BB 2
#define SS 2048
#define DIM 1024
#define NH 16
#define DH 64

typedef __bf16 bf16x8 __attribute__((ext_vector_type(8)));
typedef float f32x4 __attribute__((ext_vector_type(4)));

__device__ __forceinline__ void glds16(const __hip_bfloat16* g, __hip_bfloat16* l) {
    __builtin_amdgcn_global_load_lds(
        (const __attribute__((address_space(1))) void*)g,
        (__attribute__((address_space(3))) void*)l, 16, 0, 0);
}

// ---------------- prep: split fp32 -> bf16 hi + lo ----------------
__global__ void split_f32(const float4* __restrict__ in,
                          ushort4* __restrict__ hi, ushort4* __restrict__ lo) {
    int i = blockIdx.x * 256 + threadIdx.x;
    float4 v = in[i];
    ushort4 h, l;
    __hip_bfloat16 t;
    t = __float2bfloat16(v.x); h.x = *(ushort*)&t; t = __float2bfloat16(v.x - __bfloat162float(t)); l.x = *(ushort*)&t;
    t = __float2bfloat16(v.y); h.y = *(ushort*)&t; t = __float2bfloat16(v.y - __bfloat162float(t)); l.y = *(ushort*)&t;
    t = __float2bfloat16(v.z); h.z = *(ushort*)&t; t = __float2bfloat16(v.z - __bfloat162float(t)); l.z = *(ushort*)&t;
    t = __float2bfloat16(v.w); h.w = *(ushort*)&t; t = __float2bfloat16(v.w - __bfloat162float(t)); l.w = *(ushort*)&t;
    hi[i] = h; lo[i] = l;
}

// ------- prep: transpose all 4 W [K,N] -> [N,K], split hi/lo (one launch) -------
__global__ void trans_split4(const float* __restrict__ Wq, const float* __restrict__ Wk,
                             const float* __restrict__ Wv, const float* __restrict__ Wo,
                             __hip_bfloat16* __restrict__ T3hi, __hip_bfloat16* __restrict__ T3lo,
                             __hip_bfloat16* __restrict__ Tohi, __hip_bfloat16* __restrict__ Tolo) {
    int z = blockIdx.z;
    const float* W = (z == 0) ? Wq : (z == 1) ? Wk : (z == 2) ? Wv : Wo;
    __hip_bfloat16* Thi = (z < 3) ? T3hi + (size_t)z * DIM * DIM : Tohi;
    __hip_bfloat16* Tlo = (z < 3) ? T3lo + (size_t)z * DIM * DIM : Tolo;
    __shared__ float tile[32][33];
    int k0 = blockIdx.x * 32, n0 = blockIdx.y * 32;
    int t = threadIdx.x;
    int r = t >> 3, c = (t & 7) << 2;
    float4 v = *(const float4*)&W[(size_t)(k0 + r) * DIM + n0 + c];
    tile[r][c] = v.x; tile[r][c + 1] = v.y; tile[r][c + 2] = v.z; tile[r][c + 3] = v.w;
    __syncthreads();
    size_t base = (size_t)(n0 + r) * DIM + k0 + c;
#pragma unroll
    for (int i = 0; i < 4; ++i) {
        float x = tile[c + i][r];
        __hip_bfloat16 h = __float2bfloat16(x);
        Thi[base + i] = h;
        Tlo[base + i] = __float2bfloat16(x - __bfloat162float(h));
    }
}

// ---------------- split-bf16 3-term MFMA GEMM ----------------
// mode 0: of32[m*1024+n] = acc + b0[n]
// mode 1: fused QKV, N=3072: n<1024 -> Q split-heads, <2048 -> K split-heads,
//         else V^T [B,H,DH,S]
#define BM 128
#define BN 64
#define BK 32
__global__ __launch_bounds__(256) void gemm3term(
    const __hip_bfloat16* __restrict__ Ahi, const __hip_bfloat16* __restrict__ Alo,
    const __hip_bfloat16* __restrict__ Bhi, const __hip_bfloat16* __restrict__ Blo,
    const float* __restrict__ b0, const float* __restrict__ b1, const float* __restrict__ b2,
    __hip_bfloat16* __restrict__ oq, __hip_bfloat16* __restrict__ ok,
    __hip_bfloat16* __restrict__ ov, float* __restrict__ of32, int mode) {
    __shared__ alignas(16) __hip_bfloat16 sAh[BM * BK];
    __shared__ alignas(16) __hip_bfloat16 sAl[BM * BK];
    __shared__ alignas(16) __hip_bfloat16 sBh[BN * BK];
    __shared__ alignas(16) __hip_bfloat16 sBl[BN * BK];
    const int K = 1024;
    int tid = threadIdx.x;
    int wave = tid >> 6, lane = tid & 63, quad = lane >> 4, l16 = lane & 15;
    int m0 = blockIdx.y * BM, n0 = blockIdx.x * BN;
    int mo = (wave >> 1) * 64, no = (wave & 1) * 32;

    f32x4 acc[4][2];
#pragma unroll
    for (int i = 0; i < 4; ++i)
#pragma unroll
        for (int j = 0; j < 2; ++j) acc[i][j] = (f32x4){0.f, 0.f, 0.f, 0.f};

    int ar = tid >> 2;
    int ac = (tid & 3) << 3;
    const __hip_bfloat16* gAh = Ahi + (size_t)(m0 + ar) * K + ac;
    const __hip_bfloat16* gAl = Alo + (size_t)(m0 + ar) * K + ac;
    const __hip_bfloat16* gBh = Bhi + (size_t)(n0 + ar) * K + ac;
    const __hip_bfloat16* gBl = Blo + (size_t)(n0 + ar) * K + ac;
    __hip_bfloat16* lAh0 = &sAh[ar * BK + ac];
    __hip_bfloat16* lAh1 = &sAh[(ar + 64) * BK + ac];
    __hip_bfloat16* lAl0 = &sAl[ar * BK + ac];
    __hip_bfloat16* lAl1 = &sAl[(ar + 64) * BK + ac];
    __hip_bfloat16* lBh  = &sBh[ar * BK + ac];
    __hip_bfloat16* lBl  = &sBl[ar * BK + ac];

    for (int k0 = 0; k0 < K; k0 += BK) {
        __syncthreads();
        glds16(gAh + k0, lAh0);
        glds16(gAh + (size_t)64 * K + k0, lAh1);
        glds16(gAl + k0, lAl0);
        glds16(gAl + (size_t)64 * K + k0, lAl1);
        glds16(gBh + k0, lBh);
        glds16(gBl + k0, lBl);
        __syncthreads();

        bf16x8 a_h[4], a_l[4], b_h[2], b_l[2];
#pragma unroll
        for (int i = 0; i < 4; ++i) {
            int off = (mo + i * 16 + l16) * BK + quad * 8;
            a_h[i] = *(const bf16x8*)&sAh[off];
            a_l[i] = *(const bf16x8*)&sAl[off];
        }
#pragma unroll
        for (int j = 0; j < 2; ++j) {
            int off = (no + j * 16 + l16) * BK + quad * 8;
            b_h[j] = *(const bf16x8*)&sBh[off];
            b_l[j] = *(const bf16x8*)&sBl[off];
        }
#pragma unroll
        for (int i = 0; i < 4; ++i)
#pragma unroll
            for (int j = 0; j < 2; ++j) {
                acc[i][j] = __builtin_amdgcn_mfma_f32_16x16x32_bf16(a_h[i], b_h[j], acc[i][j], 0, 0, 0);
                acc[i][j] = __builtin_amdgcn_mfma_f32_16x16x32_bf16(a_h[i], b_l[j], acc[i][j], 0, 0, 0);
                acc[i][j] = __builtin_amdgcn_mfma_f32_16x16x32_bf16(a_l[i], b_h[j], acc[i][j], 0, 0, 0);
            }
    }

    int which = (mode == 1) ? (n0 >> 10) : 0;
    const float* bp = (mode == 0) ? b0 : (which == 0) ? b0 : (which == 1) ? b1 : b2;
#pragma unroll
    for (int i = 0; i < 4; ++i)
#pragma unroll
        for (int j = 0; j < 2; ++j) {
            int gmb = m0 + mo + i * 16 + quad * 4;
            int gn  = n0 + no + j * 16 + l16;
            int nn  = gn & 1023;
            float bb = bp[(mode == 0) ? gn : nn];
#pragma unroll
            for (int r = 0; r < 4; ++r) {
                int gm = gmb + r;
                float v = acc[i][j][r] + bb;
                if (mode == 0) {
                    of32[(size_t)gm * 1024 + gn] = v;
                } else {
                    int b = gm >> 11, s = gm & 2047, h = nn >> 6, d = nn & 63;
                    if (which == 0)
                        oq[(((size_t)(b * NH + h)) * SS + s) * DH + d] = __float2bfloat16(v);
                    else if (which == 1)
                        ok[(((size_t)(b * NH + h)) * SS + s) * DH + d] = __float2bfloat16(v);
                    else
                        ov[(((size_t)(b * NH + h)) * DH + d) * SS + s] = __float2bfloat16(v);
                }
            }
        }
}

// ---------------- flash attention v2: K-tile 128, ones-MFMA row sums ----------------
// Q,K: [B,H,S,DH] bf16.  Vt: [B,H,DH,S] bf16.  ctx out: hi/lo bf16 [B,S,H*DH].
// log2-domain softmax: scores scaled by 0.125*log2(e), exp2 everywhere.
#define PSTRIDE 132   // bf16 elems; 264 B = 66 dwords -> quad rows on disjoint 8-bank windows
__global__ __launch_bounds__(256) void flash_attn(
        const __hip_bfloat16* __restrict__ Q,
        const __hip_bfloat16* __restrict__ K,
        const __hip_bfloat16* __restrict__ Vt,
        const float* __restrict__ mask,
        __hip_bfloat16* __restrict__ chi,
        __hip_bfloat16* __restrict__ clo) {
    int bh = blockIdx.y;
    int b = bh >> 4, h = bh & (NH - 1);
    int q0 = blockIdx.x * 64;
    int tid = threadIdx.x;
    int wave = tid >> 6, lane = tid & 63, quad = lane >> 4, l16 = lane & 15;

    __shared__ __hip_bfloat16 Pl[4][16][PSTRIDE];

    const float SC  = 0.125f * 1.44269504f;      // score scale in log2 domain
    const float PEN = 1000000.0f * 1.44269504f;  // mask penalty in log2 domain

    const __hip_bfloat16* Qrow = Q + ((size_t)bh * SS + q0 + wave * 16 + l16) * DH;
    bf16x8 aq0 = *(const bf16x8*)(Qrow + quad * 8);
    bf16x8 aq1 = *(const bf16x8*)(Qrow + 32 + quad * 8);

    const __hip_bfloat16* Kbase = K + (size_t)bh * SS * DH;
    const __hip_bfloat16* Vbase = Vt + (size_t)bh * DH * SS;
    const float* mbase = mask + b * SS;

    bf16x8 vones;
#pragma unroll
    for (int j = 0; j < 8; ++j) vones[j] = (__bf16)1.0f;

    f32x4 O[4];
#pragma unroll
    for (int i = 0; i < 4; ++i) O[i] = (f32x4){0.f, 0.f, 0.f, 0.f};
    f32x4 lacc = (f32x4){0.f, 0.f, 0.f, 0.f};
    float mrow[4] = {-1e30f, -1e30f, -1e30f, -1e30f};

    for (int k0 = 0; k0 < SS; k0 += 128) {
        // ---- S (16x128) = Q K^T, log2 domain, minus mask penalty
        f32x4 S[8];
#pragma unroll
        for (int nb = 0; nb < 8; ++nb) {
            const __hip_bfloat16* Kr = Kbase + (size_t)(k0 + nb * 16 + l16) * DH + quad * 8;
            bf16x8 bk0 = *(const bf16x8*)(Kr);
            bf16x8 bk1 = *(const bf16x8*)(Kr + 32);
            f32x4 s = (f32x4){0.f, 0.f, 0.f, 0.f};
            s = __builtin_amdgcn_mfma_f32_16x16x32_bf16(aq0, bk0, s, 0, 0, 0);
            s = __builtin_amdgcn_mfma_f32_16x16x32_bf16(aq1, bk1, s, 0, 0, 0);
            float pen = PEN * (1.0f - mbase[k0 + nb * 16 + l16]);
#pragma unroll
            for (int r = 0; r < 4; ++r) s[r] = s[r] * SC - pen;
            S[nb] = s;
        }
        // ---- row max: in-lane over 8 blocks, then 4-step xor across 16 lanes
        f32x4 vm = S[0];
#pragma unroll
        for (int nb = 1; nb < 8; ++nb)
#pragma unroll
            for (int r = 0; r < 4; ++r) vm[r] = fmaxf(vm[r], S[nb][r]);
        float rm[4] = {vm[0], vm[1], vm[2], vm[3]};
#pragma unroll
        for (int off = 1; off < 16; off <<= 1)
#pragma unroll
            for (int r = 0; r < 4; ++r)
                rm[r] = fmaxf(rm[r], __shfl_xor(rm[r], off, 64));
        float alpha[4];
#pragma unroll
        for (int r = 0; r < 4; ++r) {
            float mn = fmaxf(mrow[r], rm[r]);
            alpha[r] = exp2f(mrow[r] - mn);
            mrow[r] = mn;
        }
        // ---- P = exp2(S - m) -> LDS (conflict-free stride)
#pragma unroll
        for (int nb = 0; nb < 8; ++nb)
#pragma unroll
            for (int r = 0; r < 4; ++r)
                Pl[wave][quad * 4 + r][nb * 16 + l16] = __float2bfloat16(exp2f(S[nb][r] - mrow[r]));
        // ---- rescale O and l-accumulator
#pragma unroll
        for (int i = 0; i < 4; ++i)
#pragma unroll
            for (int r = 0; r < 4; ++r) O[i][r] *= alpha[r];
#pragma unroll
        for (int r = 0; r < 4; ++r) lacc[r] *= alpha[r];
        // ---- P fragments (A-layout) from LDS
        bf16x8 ap[4];
#pragma unroll
        for (int f = 0; f < 4; ++f)
            ap[f] = *(const bf16x8*)(&Pl[wave][l16][f * 32 + quad * 8]);
        // ---- l += rowsum(P) via ones-MFMA
#pragma unroll
        for (int f = 0; f < 4; ++f)
            lacc = __builtin_amdgcn_mfma_f32_16x16x32_bf16(ap[f], vones, lacc, 0, 0, 0);
        // ---- O += P @ V
#pragma unroll
        for (int nb2 = 0; nb2 < 4; ++nb2) {
            const __hip_bfloat16* Vr = Vbase + (size_t)(nb2 * 16 + l16) * SS + k0 + quad * 8;
#pragma unroll
            for (int f = 0; f < 4; ++f) {
                bf16x8 bv = *(const bf16x8*)(Vr + f * 32);
                O[nb2] = __builtin_amdgcn_mfma_f32_16x16x32_bf16(ap[f], bv, O[nb2], 0, 0, 0);
            }
        }
    }
    // ---- epilogue
#pragma unroll
    for (int nb2 = 0; nb2 < 4; ++nb2)
#pragma unroll
        for (int r = 0; r < 4; ++r) {
            size_t row = (size_t)b * SS + q0 + wave * 16 + quad * 4 + r;
            float v = O[nb2][r] / lacc[r];
            size_t idx = row * (NH * DH) + h * DH + nb2 * 16 + l16;
            __hip_bfloat16 hi = __float2bfloat16(v);
            chi[idx] = hi;
            clo[idx] = __float2bfloat16(v - __bfloat162float(hi));
        }
}

extern "C" void kernel_launch(void* const* d_in, const int* in_sizes, int n_in,
                              void* d_out, int out_size, void* d_ws, size_t ws_size,
                              hipStream_t stream) {
    const float* X    = (const float*)d_in[0];
    const float* mask = (const float*)d_in[1];
    const float* Wq   = (const float*)d_in[2];
    const float* bq   = (const float*)d_in[3];
    const float* Wk   = (const float*)d_in[4];
    const float* bk   = (const float*)d_in[5];
    const float* Wv   = (const float*)d_in[6];
    const float* bv   = (const float*)d_in[7];
    const float* Wo   = (const float*)d_in[8];
    const float* bo   = (const float*)d_in[9];
    float* out = (float*)d_out;

    const size_t MB = 1u << 20;
    char* ws = (char*)d_ws;
    __hip_bfloat16* Xhi   = (__hip_bfloat16*)(ws);            // 8 MB (later ctx_hi)
    __hip_bfloat16* Xlo   = (__hip_bfloat16*)(ws + 8 * MB);   // 8 MB (later ctx_lo)
    __hip_bfloat16* Wt3hi = (__hip_bfloat16*)(ws + 16 * MB);  // 6 MB [3072,1024]
    __hip_bfloat16* Wt3lo = (__hip_bfloat16*)(ws + 22 * MB);  // 6 MB
    __hip_bfloat16* Wothi = (__hip_bfloat16*)(ws + 28 * MB);  // 2 MB
    __hip_bfloat16* Wotlo = (__hip_bfloat16*)(ws + 30 * MB);  // 2 MB
    __hip_bfloat16* Qw    = (__hip_bfloat16*)(ws + 32 * MB);  // 8 MB
    __hip_bfloat16* Kw    = (__hip_bfloat16*)(ws + 40 * MB);  // 8 MB
    __hip_bfloat16* Vt    = (__hip_bfloat16*)(ws + 48 * MB);  // 8 MB

    split_f32<<<4096, 256, 0, stream>>>((const float4*)X, (ushort4*)Xhi, (ushort4*)Xlo);

    dim3 tgrd(32, 32, 4);
    trans_split4<<<tgrd, 256, 0, stream>>>(Wq, Wk, Wv, Wo, Wt3hi, Wt3lo, Wothi, Wotlo);

    // fused QKV: N = 3072
    dim3 qkvgrd(3 * DIM / BN, (BB * SS) / BM);   // (48, 32)
    gemm3term<<<qkvgrd, 256, 0, stream>>>(Xhi, Xlo, Wt3hi, Wt3lo, bq, bk, bv,
                                          Qw, Kw, Vt, nullptr, 1);

    dim3 agrd(SS / 64, BB * NH);
    flash_attn<<<agrd, 256, 0, stream>>>(Qw, Kw, Vt, mask, Xhi, Xlo);

    dim3 ogrd(DIM / BN, (BB * SS) / BM);         // (16, 32)
    gemm3term<<<ogrd, 256, 0, stream>>>(Xhi, Xlo, Wothi, Wotlo, bo, nullptr, nullptr,
                                        nullptr, nullptr, nullptr, out, 0);
}